// Round 1
// baseline (197.881 us; speedup 1.0000x reference)
//
#include <hip/hip_runtime.h>
#include <stdint.h>

#define RX 128
#define ROWS 4096   // BS*UE*RX
#define NBU 32      // BS*UE

typedef __attribute__((ext_vector_type(8))) short short8;   // 8 bf16 (4 VGPRs)
typedef __attribute__((ext_vector_type(4))) float f32x4;

// ws layout (floats):
//   R1 @ 0        [4096*64]   dot(x_row, W1[:,  0: 64])
//   R2 @ 262144   [4096*64]   dot(x_row, W1[:, 64:128])
//   R3 @ 524288   [4096*64]   dot(x_row, W1[:,128:192])
//   r4 @ 786432   [32*64]     dot(m_bu,  W1[:,192:256])
//   r5b@ 788480   [32*64]     dot(m_bu,  W1[:,256:320]) + b1
#define WS_R1 0
#define WS_R2 262144
#define WS_R3 524288
#define WS_R4 786432
#define WS_R5 788480

__device__ __forceinline__ short bf16rne(float f) {
    uint32_t u = __float_as_uint(f);
    u += 0x7FFFu + ((u >> 16) & 1u);
    return (short)(u >> 16);
}

// load 16 floats (two 8-float halves at d0 and d1) into o[0..15]
__device__ __forceinline__ void ld16f(const float* __restrict__ p, int d0, int d1,
                                      float* __restrict__ o) {
    *(float4*)(o + 0)  = *(const float4*)(p + d0);
    *(float4*)(o + 4)  = *(const float4*)(p + d0 + 4);
    *(float4*)(o + 8)  = *(const float4*)(p + d1);
    *(float4*)(o + 12) = *(const float4*)(p + d1 + 4);
}

// ---------------- kernel 1: precompute R1,R2,R3 (blocks 0..511) and r4,r5b (512..543)
__global__ __launch_bounds__(192) void k_pre(const float* __restrict__ x,
                                             const float* __restrict__ W1,
                                             const float* __restrict__ b1,
                                             float* __restrict__ ws) {
    __shared__ float s[8256];
    const int t = threadIdx.x;
    const int blk = blockIdx.x;

    if (blk < 512) {
        const int r0 = blk * 8;                       // 8 rows of Xall per block
        if (t < 128)
            ((float4*)s)[t] = ((const float4*)(x + r0 * 64))[t];
        __syncthreads();
        const int arr = t >> 6;                       // 0->R1, 1->R2, 2->R3
        const int dp  = t & 63;
        const float* wrow = W1 + dp * 320 + arr * 64; // W1[dp][arr*64 + f]
        float4 w[16];
#pragma unroll
        for (int fc = 0; fc < 16; ++fc) w[fc] = ((const float4*)wrow)[fc];
        float* dst = ws + (arr == 0 ? WS_R1 : arr == 1 ? WS_R2 : WS_R3);
#pragma unroll
        for (int r = 0; r < 8; ++r) {
            float acc = 0.f;
#pragma unroll
            for (int fc = 0; fc < 16; ++fc) {
                float4 xv = ((const float4*)(s + r * 64))[fc];
                acc = fmaf(xv.x, w[fc].x, acc);
                acc = fmaf(xv.y, w[fc].y, acc);
                acc = fmaf(xv.z, w[fc].z, acc);
                acc = fmaf(xv.w, w[fc].w, acc);
            }
            dst[(r0 + r) * 64 + dp] = acc;
        }
    } else {
        const int bu = blk - 512;
        const float* xb = x + bu * RX * 64;
        for (int idx = t; idx < 2048; idx += 192)
            ((float4*)s)[idx] = ((const float4*)xb)[idx];
        __syncthreads();
        if (t < 64) {                                  // column means
            float a0 = 0, a1 = 0, a2 = 0, a3 = 0;
            for (int r = 0; r < 128; r += 4) {
                a0 += s[(r + 0) * 64 + t];
                a1 += s[(r + 1) * 64 + t];
                a2 += s[(r + 2) * 64 + t];
                a3 += s[(r + 3) * 64 + t];
            }
            s[8192 + t] = (a0 + a1 + a2 + a3) * (1.0f / 128.0f);
        }
        __syncthreads();
        if (t < 128) {
            const int dp = t & 63, which = t >> 6;     // 0->r4, 1->r5b
            const float* wrow = W1 + dp * 320 + 192 + which * 64;
            float acc = which ? b1[dp] : 0.f;
#pragma unroll
            for (int fc = 0; fc < 16; ++fc) {
                float4 mv = ((const float4*)(s + 8192))[fc];
                float4 wv = ((const float4*)wrow)[fc];
                acc = fmaf(mv.x, wv.x, acc);
                acc = fmaf(mv.y, wv.y, acc);
                acc = fmaf(mv.z, wv.z, acc);
                acc = fmaf(mv.w, wv.w, acc);
            }
            (ws + (which ? WS_R5 : WS_R4))[bu * 64 + dp] = acc;
        }
    }
}

// ---------------- kernel 2: one block per (bu, i); LN + relu + diag-bias + fc2(MFMA)
__global__ __launch_bounds__(256) void k_main(const float* __restrict__ ws,
                                              const float* __restrict__ ln_g,
                                              const float* __restrict__ ln_b,
                                              const float* __restrict__ bias,
                                              const float* __restrict__ W2,
                                              const float* __restrict__ b2,
                                              float* __restrict__ out) {
    const float* R1  = ws + WS_R1;
    const float* R2  = ws + WS_R2;
    const float* R3  = ws + WS_R3;
    const float* r4  = ws + WS_R4;
    const float* r5b = ws + WS_R5;

    const int t    = threadIdx.x;
    const int lane = t & 63;
    const int wid  = t >> 6;        // wave id 0..3
    const int q    = lane >> 4;     // quad 0..3
    const int ml   = lane & 15;
    const int row  = blockIdx.x;    // bu*128 + i
    const int bu   = row >> 7;
    const int i    = row & 127;

    const int d0 = q * 8;           // k-tile 0 d-range [d0, d0+8)
    const int d1 = 32 + q * 8;      // k-tile 1 d-range [d1, d1+8)

    // per-lane constants over d-set
    float basev[16], tmp[16], gv[16], bbv[16];
    ld16f(R2 + row * 64, d0, d1, basev);
    ld16f(r5b + bu * 64, d0, d1, tmp);
#pragma unroll
    for (int s = 0; s < 16; ++s) basev[s] += tmp[s];
    ld16f(ln_g, d0, d1, gv);
    ld16f(ln_b, d0, d1, bbv);

    // W2 B-fragments: B[k=q*8+jj][n=ml] = W2[ot*16+ml][kt*32 + q*8 + jj]
    short8 bf[4][2];
#pragma unroll
    for (int ot = 0; ot < 4; ++ot) {
#pragma unroll
        for (int kt = 0; kt < 2; ++kt) {
            const float* wp = W2 + (ot * 16 + ml) * 64 + kt * 32 + q * 8;
            float4 w0 = *(const float4*)wp;
            float4 w1 = *(const float4*)(wp + 4);
            short8 v;
            v[0] = bf16rne(w0.x); v[1] = bf16rne(w0.y);
            v[2] = bf16rne(w0.z); v[3] = bf16rne(w0.w);
            v[4] = bf16rne(w1.x); v[5] = bf16rne(w1.y);
            v[6] = bf16rne(w1.z); v[7] = bf16rne(w1.w);
            bf[ot][kt] = v;
        }
    }
    float b2v[4];
#pragma unroll
    for (int ot = 0; ot < 4; ++ot) b2v[ot] = b2[ot * 16 + ml];

    const float* r3base = R3 + (size_t)bu * 128 * 64;
    float* outB = out + (size_t)row * 8192;
    const int it = i >> 4, im = i & 15;

#pragma unroll
    for (int p = 0; p < 2; ++p) {
        const int jt = p * 4 + wid;      // j-tile handled by this wave this pass
        const int j  = jt * 16 + ml;     // this lane's row within the tile

        float h[16];
        ld16f(r3base + j * 64, d0, d1, h);
#pragma unroll
        for (int s = 0; s < 16; ++s) h[s] += basev[s];

        const bool diag = (jt == it) && (ml == im);   // j == i
        if (jt == it) {
            if (diag) {
                float da[16], db[16];
                ld16f(R1 + row * 64, d0, d1, da);
                ld16f(r4 + bu * 64, d0, d1, db);
#pragma unroll
                for (int s = 0; s < 16; ++s) h[s] += da[s] + db[s];
            }
        }

        // LayerNorm over d=64: 16 in-lane + 4 lanes {ml, ml+16, ml+32, ml+48}
        float sum = 0.f, ss = 0.f;
#pragma unroll
        for (int s = 0; s < 16; ++s) { sum += h[s]; ss = fmaf(h[s], h[s], ss); }
        sum += __shfl_xor(sum, 16); sum += __shfl_xor(sum, 32);
        ss  += __shfl_xor(ss, 16);  ss  += __shfl_xor(ss, 32);
        const float mu  = sum * 0.015625f;
        const float var = ss * 0.015625f - mu * mu;
        const float inv = rsqrtf(var + 1e-5f);

        float y[16];
#pragma unroll
        for (int s = 0; s < 16; ++s) {
            float v = fmaf((h[s] - mu) * inv, gv[s], bbv[s]);
            y[s] = fmaxf(v, 0.f);
        }
        if (diag) {
            float bi[16];
            ld16f(bias, d0, d1, bi);
#pragma unroll
            for (int s = 0; s < 16; ++s) y[s] += bi[s];
        }

        // pack A-fragments (already in A-layout: A[m=ml][k=q*8+jj])
        short8 a0, a1;
#pragma unroll
        for (int jj = 0; jj < 8; ++jj) { a0[jj] = bf16rne(y[jj]); a1[jj] = bf16rne(y[8 + jj]); }

#pragma unroll
        for (int ot = 0; ot < 4; ++ot) {
            f32x4 acc = { b2v[ot], b2v[ot], b2v[ot], b2v[ot] };
            acc = __builtin_amdgcn_mfma_f32_16x16x32_bf16(a0, bf[ot][0], acc, 0, 0, 0);
            acc = __builtin_amdgcn_mfma_f32_16x16x32_bf16(a1, bf[ot][1], acc, 0, 0, 0);
            // D: col = lane&15 (o), row = q*4 + reg (j within tile)
            float* ob = outB + (size_t)(jt * 16 + q * 4) * 64 + ot * 16 + ml;
            ob[0]   = acc[0];
            ob[64]  = acc[1];
            ob[128] = acc[2];
            ob[192] = acc[3];
        }
    }
}

extern "C" void kernel_launch(void* const* d_in, const int* in_sizes, int n_in,
                              void* d_out, int out_size, void* d_ws, size_t ws_size,
                              hipStream_t stream) {
    const float* x    = (const float*)d_in[0];
    const float* W1   = (const float*)d_in[1];
    const float* b1   = (const float*)d_in[2];
    const float* ln_g = (const float*)d_in[3];
    const float* ln_b = (const float*)d_in[4];
    const float* bias = (const float*)d_in[5];
    const float* W2   = (const float*)d_in[6];
    const float* b2   = (const float*)d_in[7];
    float* ws  = (float*)d_ws;
    float* out = (float*)d_out;

    hipLaunchKernelGGL(k_pre, dim3(544), dim3(192), 0, stream, x, W1, b1, ws);
    hipLaunchKernelGGL(k_main, dim3(4096), dim3(256), 0, stream,
                       ws, ln_g, ln_b, bias, W2, b2, out);
}

// Round 2
// 174.975 us; speedup vs baseline: 1.1309x; 1.1309x over previous
//
#include <hip/hip_runtime.h>
#include <stdint.h>

#define RX 128
#define ROWS 4096   // BS*UE*RX
#define NBU 32      // BS*UE

typedef __attribute__((ext_vector_type(8))) short short8;   // 8 bf16 (4 VGPRs)
typedef __attribute__((ext_vector_type(4))) float f32x4;

// ws layout (floats):
//   R1 @ 0        [4096*64]   dot(x_row, W1[:,  0: 64])
//   R2 @ 262144   [4096*64]   dot(x_row, W1[:, 64:128])
//   R3 @ 524288   [4096*64]   dot(x_row, W1[:,128:192])
//   r4 @ 786432   [32*64]     dot(m_bu,  W1[:,192:256])
//   r5b@ 788480   [32*64]     dot(m_bu,  W1[:,256:320]) + b1
#define WS_R1 0
#define WS_R2 262144
#define WS_R3 524288
#define WS_R4 786432
#define WS_R5 788480

#define LDP 68      // padded row stride (floats) for the LDS R3 tile

__device__ __forceinline__ short bf16rne(float f) {
    uint32_t u = __float_as_uint(f);
    u += 0x7FFFu + ((u >> 16) & 1u);
    return (short)(u >> 16);
}

// load 16 floats (two 8-float halves at d0 and d1) into o[0..15]
__device__ __forceinline__ void ld16f(const float* __restrict__ p, int d0, int d1,
                                      float* __restrict__ o) {
    *(float4*)(o + 0)  = *(const float4*)(p + d0);
    *(float4*)(o + 4)  = *(const float4*)(p + d0 + 4);
    *(float4*)(o + 8)  = *(const float4*)(p + d1);
    *(float4*)(o + 12) = *(const float4*)(p + d1 + 4);
}

// ---------------- kernel 1: precompute R1,R2,R3 (blocks 0..511) and r4,r5b (512..543)
__global__ __launch_bounds__(192) void k_pre(const float* __restrict__ x,
                                             const float* __restrict__ W1,
                                             const float* __restrict__ b1,
                                             float* __restrict__ ws) {
    __shared__ float s[8256];
    const int t = threadIdx.x;
    const int blk = blockIdx.x;

    if (blk < 512) {
        const int r0 = blk * 8;                       // 8 rows of Xall per block
        if (t < 128)
            ((float4*)s)[t] = ((const float4*)(x + r0 * 64))[t];
        __syncthreads();
        const int arr = t >> 6;                       // 0->R1, 1->R2, 2->R3
        const int dp  = t & 63;
        const float* wrow = W1 + dp * 320 + arr * 64; // W1[dp][arr*64 + f]
        float4 w[16];
#pragma unroll
        for (int fc = 0; fc < 16; ++fc) w[fc] = ((const float4*)wrow)[fc];
        float* dst = ws + (arr == 0 ? WS_R1 : arr == 1 ? WS_R2 : WS_R3);
#pragma unroll
        for (int r = 0; r < 8; ++r) {
            float acc = 0.f;
#pragma unroll
            for (int fc = 0; fc < 16; ++fc) {
                float4 xv = ((const float4*)(s + r * 64))[fc];
                acc = fmaf(xv.x, w[fc].x, acc);
                acc = fmaf(xv.y, w[fc].y, acc);
                acc = fmaf(xv.z, w[fc].z, acc);
                acc = fmaf(xv.w, w[fc].w, acc);
            }
            dst[(r0 + r) * 64 + dp] = acc;
        }
    } else {
        const int bu = blk - 512;
        const float* xb = x + bu * RX * 64;
        for (int idx = t; idx < 2048; idx += 192)
            ((float4*)s)[idx] = ((const float4*)xb)[idx];
        __syncthreads();
        if (t < 64) {                                  // column means
            float a0 = 0, a1 = 0, a2 = 0, a3 = 0;
            for (int r = 0; r < 128; r += 4) {
                a0 += s[(r + 0) * 64 + t];
                a1 += s[(r + 1) * 64 + t];
                a2 += s[(r + 2) * 64 + t];
                a3 += s[(r + 3) * 64 + t];
            }
            s[8192 + t] = (a0 + a1 + a2 + a3) * (1.0f / 128.0f);
        }
        __syncthreads();
        if (t < 128) {
            const int dp = t & 63, which = t >> 6;     // 0->r4, 1->r5b
            const float* wrow = W1 + dp * 320 + 192 + which * 64;
            float acc = which ? b1[dp] : 0.f;
#pragma unroll
            for (int fc = 0; fc < 16; ++fc) {
                float4 mv = ((const float4*)(s + 8192))[fc];
                float4 wv = ((const float4*)wrow)[fc];
                acc = fmaf(mv.x, wv.x, acc);
                acc = fmaf(mv.y, wv.y, acc);
                acc = fmaf(mv.z, wv.z, acc);
                acc = fmaf(mv.w, wv.w, acc);
            }
            (ws + (which ? WS_R5 : WS_R4))[bu * 64 + dp] = acc;
        }
    }
}

// ---------------- kernel 2: one block per (bu, i-pair); LN + relu + diag-bias + fc2(MFMA)
// grid 2048: blockIdx = bu*64 + ipair; rows handled: bu*128 + ipair*2 + {0,1}
__global__ __launch_bounds__(256) void k_main(const float* __restrict__ ws,
                                              const float* __restrict__ ln_g,
                                              const float* __restrict__ ln_b,
                                              const float* __restrict__ bias,
                                              const float* __restrict__ W2,
                                              const float* __restrict__ b2,
                                              float* __restrict__ out) {
    const float* R1  = ws + WS_R1;
    const float* R2  = ws + WS_R2;
    const float* R3  = ws + WS_R3;
    const float* r4  = ws + WS_R4;
    const float* r5b = ws + WS_R5;

    __shared__ float sR3[128 * LDP];   // 34816 B, +4-float pad per row

    const int t    = threadIdx.x;
    const int lane = t & 63;
    const int wid  = t >> 6;        // wave id 0..3
    const int q    = lane >> 4;     // quad 0..3
    const int ml   = lane & 15;
    const int bu   = blockIdx.x >> 6;
    const int i0   = (blockIdx.x & 63) * 2;

    const int d0 = q * 8;           // k-tile 0 d-range [d0, d0+8)
    const int d1 = 32 + q * 8;      // k-tile 1 d-range [d1, d1+8)

    // ---- stage R3[bu] (128x64) into LDS, coalesced, padded rows
    {
        const float* r3g = R3 + (size_t)bu * 8192;
#pragma unroll
        for (int c = 0; c < 8; ++c) {
            const int g = c * 256 + t;            // float4 index 0..2047
            const int r = g >> 4, col = (g & 15) << 2;
            *(float4*)&sR3[r * LDP + col] = ((const float4*)r3g)[g];
        }
    }

    // ---- per-lane constants over this lane's d-set
    float r5v[16], gv[16], bbv[16];
    ld16f(r5b + bu * 64, d0, d1, r5v);
    ld16f(ln_g, d0, d1, gv);
    ld16f(ln_b, d0, d1, bbv);

    // W2 B-fragments: B[k=q*8+jj][n=ml] = W2[ot*16+ml][kt*32 + q*8 + jj]
    short8 bf[4][2];
#pragma unroll
    for (int ot = 0; ot < 4; ++ot) {
#pragma unroll
        for (int kt = 0; kt < 2; ++kt) {
            const float* wp = W2 + (ot * 16 + ml) * 64 + kt * 32 + q * 8;
            float4 w0 = *(const float4*)wp;
            float4 w1 = *(const float4*)(wp + 4);
            short8 v;
            v[0] = bf16rne(w0.x); v[1] = bf16rne(w0.y);
            v[2] = bf16rne(w0.z); v[3] = bf16rne(w0.w);
            v[4] = bf16rne(w1.x); v[5] = bf16rne(w1.y);
            v[6] = bf16rne(w1.z); v[7] = bf16rne(w1.w);
            bf[ot][kt] = v;
        }
    }
    float b2v[4];
#pragma unroll
    for (int ot = 0; ot < 4; ++ot) b2v[ot] = b2[ot * 16 + ml];

    __syncthreads();

#pragma unroll
    for (int ip = 0; ip < 2; ++ip) {
        const int i   = i0 + ip;
        const int row = bu * 128 + i;
        const int it  = i >> 4, im = i & 15;

        float basev[16], tmp[16];
        ld16f(R2 + (size_t)row * 64, d0, d1, basev);
#pragma unroll
        for (int s = 0; s < 16; ++s) basev[s] += r5v[s];

        float* outB = out + (size_t)row * 8192;

#pragma unroll
        for (int p = 0; p < 2; ++p) {
            const int jt = p * 4 + wid;      // j-tile handled by this wave this pass
            const int j  = jt * 16 + ml;     // this lane's row within the tile

            float h[16];
            {
                const float* sp = sR3 + j * LDP;
                *(float4*)(h + 0)  = *(const float4*)(sp + d0);
                *(float4*)(h + 4)  = *(const float4*)(sp + d0 + 4);
                *(float4*)(h + 8)  = *(const float4*)(sp + d1);
                *(float4*)(h + 12) = *(const float4*)(sp + d1 + 4);
            }
#pragma unroll
            for (int s = 0; s < 16; ++s) h[s] += basev[s];

            const bool diag = (jt == it) && (ml == im);   // j == i
            if (diag) {
                float da[16], db[16];
                ld16f(R1 + (size_t)row * 64, d0, d1, da);
                ld16f(r4 + bu * 64, d0, d1, db);
#pragma unroll
                for (int s = 0; s < 16; ++s) h[s] += da[s] + db[s];
            }

            // LayerNorm over d=64: 16 in-lane + lanes {ml, ml+16, ml+32, ml+48}
            float sum = 0.f, ss = 0.f;
#pragma unroll
            for (int s = 0; s < 16; ++s) { sum += h[s]; ss = fmaf(h[s], h[s], ss); }
            sum += __shfl_xor(sum, 16); sum += __shfl_xor(sum, 32);
            ss  += __shfl_xor(ss, 16);  ss  += __shfl_xor(ss, 32);
            const float mu  = sum * 0.015625f;
            const float var = ss * 0.015625f - mu * mu;
            const float inv = rsqrtf(var + 1e-5f);

            float y[16];
#pragma unroll
            for (int s = 0; s < 16; ++s) {
                float v = fmaf((h[s] - mu) * inv, gv[s], bbv[s]);
                y[s] = fmaxf(v, 0.f);
            }
            if (diag) {
                float bi[16];
                ld16f(bias, d0, d1, bi);
#pragma unroll
                for (int s = 0; s < 16; ++s) y[s] += bi[s];
            }

            // pack A-fragments (already in A-layout: A[m=ml][k=q*8+jj])
            short8 a0, a1;
#pragma unroll
            for (int jj = 0; jj < 8; ++jj) { a0[jj] = bf16rne(y[jj]); a1[jj] = bf16rne(y[8 + jj]); }

#pragma unroll
            for (int ot = 0; ot < 4; ++ot) {
                f32x4 acc = { b2v[ot], b2v[ot], b2v[ot], b2v[ot] };
                acc = __builtin_amdgcn_mfma_f32_16x16x32_bf16(a0, bf[ot][0], acc, 0, 0, 0);
                acc = __builtin_amdgcn_mfma_f32_16x16x32_bf16(a1, bf[ot][1], acc, 0, 0, 0);
                // D: col = lane&15 (o), row = q*4 + reg (j within tile)
                float* ob = outB + (size_t)(jt * 16 + q * 4) * 64 + ot * 16 + ml;
                ob[0]   = acc[0];
                ob[64]  = acc[1];
                ob[128] = acc[2];
                ob[192] = acc[3];
            }
        }
    }
}

extern "C" void kernel_launch(void* const* d_in, const int* in_sizes, int n_in,
                              void* d_out, int out_size, void* d_ws, size_t ws_size,
                              hipStream_t stream) {
    const float* x    = (const float*)d_in[0];
    const float* W1   = (const float*)d_in[1];
    const float* b1   = (const float*)d_in[2];
    const float* ln_g = (const float*)d_in[3];
    const float* ln_b = (const float*)d_in[4];
    const float* bias = (const float*)d_in[5];
    const float* W2   = (const float*)d_in[6];
    const float* b2   = (const float*)d_in[7];
    float* ws  = (float*)d_ws;
    float* out = (float*)d_out;

    hipLaunchKernelGGL(k_pre, dim3(544), dim3(192), 0, stream, x, W1, b1, ws);
    hipLaunchKernelGGL(k_main, dim3(2048), dim3(256), 0, stream,
                       ws, ln_g, ln_b, bias, W2, b2, out);
}

// Round 3
// 167.918 us; speedup vs baseline: 1.1784x; 1.0420x over previous
//
#include <hip/hip_runtime.h>
#include <stdint.h>

#define RX 128
#define ROWS 4096   // BS*UE*RX
#define NBU 32      // BS*UE

typedef __attribute__((ext_vector_type(8))) short short8;   // 8 bf16 (4 VGPRs)
typedef __attribute__((ext_vector_type(4))) float f32x4;

// ws layout (floats):
//   R1 @ 0        [4096*64]   dot(x_row, W1[:,  0: 64])
//   R2 @ 262144   [4096*64]   dot(x_row, W1[:, 64:128])
//   R3 @ 524288   [4096*64]   dot(x_row, W1[:,128:192])
//   r4 @ 786432   [32*64]     dot(m_bu,  W1[:,192:256])
//   r5b@ 788480   [32*64]     dot(m_bu,  W1[:,256:320]) + b1
#define WS_R1 0
#define WS_R2 262144
#define WS_R3 524288
#define WS_R4 786432
#define WS_R5 788480

#define LDP 68      // padded row stride (floats) for the LDS R3 tile

__device__ __forceinline__ short bf16rne(float f) {
    uint32_t u = __float_as_uint(f);
    u += 0x7FFFu + ((u >> 16) & 1u);
    return (short)(u >> 16);
}

// load 16 floats (two 8-float halves at d0 and d1) into o[0..15]
__device__ __forceinline__ void ld16f(const float* __restrict__ p, int d0, int d1,
                                      float* __restrict__ o) {
    *(float4*)(o + 0)  = *(const float4*)(p + d0);
    *(float4*)(o + 4)  = *(const float4*)(p + d0 + 4);
    *(float4*)(o + 8)  = *(const float4*)(p + d1);
    *(float4*)(o + 12) = *(const float4*)(p + d1 + 4);
}

// ---------------- kernel 1: precompute R1,R2,R3 (blocks 0..511) and r4,r5b (512..543)
__global__ __launch_bounds__(192) void k_pre(const float* __restrict__ x,
                                             const float* __restrict__ W1,
                                             const float* __restrict__ b1,
                                             float* __restrict__ ws) {
    __shared__ float s[8256];
    const int t = threadIdx.x;
    const int blk = blockIdx.x;

    if (blk < 512) {
        const int r0 = blk * 8;                       // 8 rows of Xall per block
        if (t < 128)
            ((float4*)s)[t] = ((const float4*)(x + r0 * 64))[t];
        __syncthreads();
        const int arr = t >> 6;                       // 0->R1, 1->R2, 2->R3
        const int dp  = t & 63;
        const float* wrow = W1 + dp * 320 + arr * 64; // W1[dp][arr*64 + f]
        float4 w[16];
#pragma unroll
        for (int fc = 0; fc < 16; ++fc) w[fc] = ((const float4*)wrow)[fc];
        float* dst = ws + (arr == 0 ? WS_R1 : arr == 1 ? WS_R2 : WS_R3);
#pragma unroll
        for (int r = 0; r < 8; ++r) {
            float acc = 0.f;
#pragma unroll
            for (int fc = 0; fc < 16; ++fc) {
                float4 xv = ((const float4*)(s + r * 64))[fc];
                acc = fmaf(xv.x, w[fc].x, acc);
                acc = fmaf(xv.y, w[fc].y, acc);
                acc = fmaf(xv.z, w[fc].z, acc);
                acc = fmaf(xv.w, w[fc].w, acc);
            }
            dst[(r0 + r) * 64 + dp] = acc;
        }
    } else {
        const int bu = blk - 512;
        const float* xb = x + bu * RX * 64;
        for (int idx = t; idx < 2048; idx += 192)
            ((float4*)s)[idx] = ((const float4*)xb)[idx];
        __syncthreads();
        if (t < 64) {                                  // column means
            float a0 = 0, a1 = 0, a2 = 0, a3 = 0;
            for (int r = 0; r < 128; r += 4) {
                a0 += s[(r + 0) * 64 + t];
                a1 += s[(r + 1) * 64 + t];
                a2 += s[(r + 2) * 64 + t];
                a3 += s[(r + 3) * 64 + t];
            }
            s[8192 + t] = (a0 + a1 + a2 + a3) * (1.0f / 128.0f);
        }
        __syncthreads();
        if (t < 128) {
            const int dp = t & 63, which = t >> 6;     // 0->r4, 1->r5b
            const float* wrow = W1 + dp * 320 + 192 + which * 64;
            float acc = which ? b1[dp] : 0.f;
#pragma unroll
            for (int fc = 0; fc < 16; ++fc) {
                float4 mv = ((const float4*)(s + 8192))[fc];
                float4 wv = ((const float4*)wrow)[fc];
                acc = fmaf(mv.x, wv.x, acc);
                acc = fmaf(mv.y, wv.y, acc);
                acc = fmaf(mv.z, wv.z, acc);
                acc = fmaf(mv.w, wv.w, acc);
            }
            (ws + (which ? WS_R5 : WS_R4))[bu * 64 + dp] = acc;
        }
    }
}

// ---------------- kernel 2: one block per (bu, 4-row group); LN + relu + diag-bias + fc2(MFMA)
// grid 1024: blockIdx = bu*32 + ig; rows handled: bu*128 + ig*4 + {0..3}
__global__ __launch_bounds__(256) void k_main(const float* __restrict__ ws,
                                              const float* __restrict__ ln_g,
                                              const float* __restrict__ ln_b,
                                              const float* __restrict__ bias,
                                              const float* __restrict__ W2,
                                              const float* __restrict__ b2,
                                              float* __restrict__ out) {
    const float* R1  = ws + WS_R1;
    const float* R2  = ws + WS_R2;
    const float* R3  = ws + WS_R3;
    const float* r4  = ws + WS_R4;
    const float* r5b = ws + WS_R5;

    __shared__ float sR3[128 * LDP];   // 34816 B, +4-float pad per row -> 4 blocks/CU

    const int t    = threadIdx.x;
    const int lane = t & 63;
    const int wid  = t >> 6;        // wave id 0..3
    const int q    = lane >> 4;     // quad 0..3
    const int ml   = lane & 15;
    const int bu   = blockIdx.x >> 5;
    const int i0   = (blockIdx.x & 31) * 4;

    const int d0 = q * 8;           // k-tile 0 d-range [d0, d0+8)
    const int d1 = 32 + q * 8;      // k-tile 1 d-range [d1, d1+8)

    // ---- stage R3[bu] (128x64) into LDS, coalesced, padded rows
    {
        const float* r3g = R3 + (size_t)bu * 8192;
#pragma unroll
        for (int c = 0; c < 8; ++c) {
            const int g = c * 256 + t;            // float4 index 0..2047
            const int r = g >> 4, col = (g & 15) << 2;
            *(float4*)&sR3[r * LDP + col] = ((const float4*)r3g)[g];
        }
    }

    // ---- per-lane constants over this lane's d-set
    float r5v[16], gv[16], bbv[16];
    ld16f(r5b + bu * 64, d0, d1, r5v);
    ld16f(ln_g, d0, d1, gv);
    ld16f(ln_b, d0, d1, bbv);

    // W2 B-fragments: B[k=q*8+jj][n=ml] = W2[ot*16+ml][kt*32 + q*8 + jj]
    short8 bf[4][2];
#pragma unroll
    for (int ot = 0; ot < 4; ++ot) {
#pragma unroll
        for (int kt = 0; kt < 2; ++kt) {
            const float* wp = W2 + (ot * 16 + ml) * 64 + kt * 32 + q * 8;
            float4 w0 = *(const float4*)wp;
            float4 w1 = *(const float4*)(wp + 4);
            short8 v;
            v[0] = bf16rne(w0.x); v[1] = bf16rne(w0.y);
            v[2] = bf16rne(w0.z); v[3] = bf16rne(w0.w);
            v[4] = bf16rne(w1.x); v[5] = bf16rne(w1.y);
            v[6] = bf16rne(w1.z); v[7] = bf16rne(w1.w);
            bf[ot][kt] = v;
        }
    }
    float b2v[4];
#pragma unroll
    for (int ot = 0; ot < 4; ++ot) b2v[ot] = b2[ot * 16 + ml];

    __syncthreads();

#pragma unroll
    for (int ip = 0; ip < 4; ++ip) {
        const int i   = i0 + ip;
        const int row = bu * 128 + i;
        const int it  = i >> 4, im = i & 15;

        float basev[16];
        ld16f(R2 + (size_t)row * 64, d0, d1, basev);
#pragma unroll
        for (int s = 0; s < 16; ++s) basev[s] += r5v[s];

        float* outB = out + (size_t)row * 8192;

#pragma unroll
        for (int p = 0; p < 2; ++p) {
            const int jt = p * 4 + wid;      // j-tile handled by this wave this pass
            const int j  = jt * 16 + ml;     // this lane's row within the tile

            float h[16];
            {
                const float* sp = sR3 + j * LDP;
                *(float4*)(h + 0)  = *(const float4*)(sp + d0);
                *(float4*)(h + 4)  = *(const float4*)(sp + d0 + 4);
                *(float4*)(h + 8)  = *(const float4*)(sp + d1);
                *(float4*)(h + 12) = *(const float4*)(sp + d1 + 4);
            }
#pragma unroll
            for (int s = 0; s < 16; ++s) h[s] += basev[s];

            const bool diag = (jt == it) && (ml == im);   // j == i
            if (diag) {
                float da[16], db[16];
                ld16f(R1 + (size_t)row * 64, d0, d1, da);
                ld16f(r4 + bu * 64, d0, d1, db);
#pragma unroll
                for (int s = 0; s < 16; ++s) h[s] += da[s] + db[s];
            }

            // LayerNorm over d=64: 16 in-lane + lanes {ml, ml+16, ml+32, ml+48}
            float sum = 0.f, ss = 0.f;
#pragma unroll
            for (int s = 0; s < 16; ++s) { sum += h[s]; ss = fmaf(h[s], h[s], ss); }
            sum += __shfl_xor(sum, 16); sum += __shfl_xor(sum, 32);
            ss  += __shfl_xor(ss, 16);  ss  += __shfl_xor(ss, 32);
            const float mu  = sum * 0.015625f;
            const float var = ss * 0.015625f - mu * mu;
            const float inv = rsqrtf(var + 1e-5f);

            float y[16];
#pragma unroll
            for (int s = 0; s < 16; ++s) {
                float v = fmaf((h[s] - mu) * inv, gv[s], bbv[s]);
                y[s] = fmaxf(v, 0.f);
            }
            if (diag) {
                float bi[16];
                ld16f(bias, d0, d1, bi);
#pragma unroll
                for (int s = 0; s < 16; ++s) y[s] += bi[s];
            }

            // pack A-fragments (already in A-layout: A[m=ml][k=q*8+jj])
            short8 a0, a1;
#pragma unroll
            for (int jj = 0; jj < 8; ++jj) { a0[jj] = bf16rne(y[jj]); a1[jj] = bf16rne(y[8 + jj]); }

#pragma unroll
            for (int ot = 0; ot < 4; ++ot) {
                f32x4 acc = { b2v[ot], b2v[ot], b2v[ot], b2v[ot] };
                acc = __builtin_amdgcn_mfma_f32_16x16x32_bf16(a0, bf[ot][0], acc, 0, 0, 0);
                acc = __builtin_amdgcn_mfma_f32_16x16x32_bf16(a1, bf[ot][1], acc, 0, 0, 0);
                // D: col = lane&15 (o), row = q*4 + reg (j within tile)
                float* ob = outB + (size_t)(jt * 16 + q * 4) * 64 + ot * 16 + ml;
                ob[0]   = acc[0];
                ob[64]  = acc[1];
                ob[128] = acc[2];
                ob[192] = acc[3];
            }
        }
    }
}

extern "C" void kernel_launch(void* const* d_in, const int* in_sizes, int n_in,
                              void* d_out, int out_size, void* d_ws, size_t ws_size,
                              hipStream_t stream) {
    const float* x    = (const float*)d_in[0];
    const float* W1   = (const float*)d_in[1];
    const float* b1   = (const float*)d_in[2];
    const float* ln_g = (const float*)d_in[3];
    const float* ln_b = (const float*)d_in[4];
    const float* bias = (const float*)d_in[5];
    const float* W2   = (const float*)d_in[6];
    const float* b2   = (const float*)d_in[7];
    float* ws  = (float*)d_ws;
    float* out = (float*)d_out;

    hipLaunchKernelGGL(k_pre, dim3(544), dim3(192), 0, stream, x, W1, b1, ws);
    hipLaunchKernelGGL(k_main, dim3(1024), dim3(256), 0, stream,
                       ws, ln_g, ln_b, bias, W2, b2, out);
}